// Round 3
// baseline (223.436 us; speedup 1.0000x reference)
//
#include <hip/hip_runtime.h>
#include <stdint.h>
#include <math.h>

// LC_OPE: per-row Fourier outer-product embedding contraction.
// out[n,k] = (1/100) * sum_{i,j} X[n,i]*Y[n,j]*lat[n,k,i*7+j]
//
// Barrier-free wave-autonomous pipeline: each block = ONE wave owning a
// 64-row tile, double-buffered in private LDS. global_load_lds staging +
// counted s_waitcnt vmcnt(38) keeps the next tile's 38 KB in flight while
// computing the current tile (T3/T4 pattern; no __syncthreads anywhere).

#define RL      149
#define RTILE   64                     // rows per tile (1 lane = 1 row)
#define TILE_B  (RTILE * RL * 4)       // 38144 B
#define FULLCH  37                     // 37 x 1024 B chunks = 37888 B
#define OVOFF   (TILE_B - 1024)        // 37120: overlapping tail chunk (re-reads 768 B from L2)
#define GRID    2048
#define NK      3

typedef const __attribute__((address_space(1))) unsigned int as1_uint;
typedef __attribute__((address_space(3))) unsigned int as3_uint;

__device__ __forceinline__ void stage_tile(const char* __restrict__ src,
                                           char* dst, int lane) {
    // 38 wave-instructions, each 64 lanes x 16 B = 1024 B, linear LDS dest.
    #pragma unroll
    for (int ci = 0; ci < FULLCH; ++ci)
        __builtin_amdgcn_global_load_lds((as1_uint*)(src + ci * 1024 + lane * 16),
                                         (as3_uint*)(dst + ci * 1024), 16, 0, 0);
    __builtin_amdgcn_global_load_lds((as1_uint*)(src + OVOFF + lane * 16),
                                     (as3_uint*)(dst + OVOFF), 16, 0, 0);
}

__device__ __forceinline__ void compute_row(const float* __restrict__ row,
                                            float* __restrict__ dst) {
    const float OMEGA = 1.5707963267948966f;  // pi/2
    const float S2    = 1.4142135623730951f;  // sqrt(2)
    const float t0 = row[147] * OMEGA;
    const float t1 = row[148] * OMEGA;
    float X[7], Y[7];
    X[0] = 1.f; Y[0] = 1.f;
    #pragma unroll
    for (int f = 1; f <= 3; ++f) {          // fully unrolled -> static X/Y indexing
        float s, c;
        __sincosf(t0 * (float)f, &s, &c);
        X[2*f-1] = S2 * c; X[2*f] = S2 * s;
        __sincosf(t1 * (float)f, &s, &c);
        Y[2*f-1] = S2 * c; Y[2*f] = S2 * s;
    }
    float a0 = 0.f, a1 = 0.f, a2 = 0.f;
    #pragma unroll
    for (int i = 0; i < 7; ++i)
        #pragma unroll
        for (int j = 0; j < 7; ++j) {
            const float p = X[i] * Y[j];
            const int c = i * 7 + j;
            a0 = fmaf(p, row[c],      a0);
            a1 = fmaf(p, row[49 + c], a1);
            a2 = fmaf(p, row[98 + c], a2);
        }
    dst[0] = a0 * 0.01f; dst[1] = a1 * 0.01f; dst[2] = a2 * 0.01f;
}

__global__ __launch_bounds__(64)
void ope_kernel(const float* __restrict__ x, float* __restrict__ out, int nrows) {
    __shared__ __align__(16) char lds[2 * TILE_B];   // 76288 B -> 2 blocks/CU
    const int lane = threadIdx.x;                    // one wave per block
    const char* __restrict__ xb = (const char*)x;
    const int ntile = nrows / RTILE;                 // 31250 for N=2e6 (exact)
    const long long tfirst = blockIdx.x;
    const int GW = gridDim.x;

    // prolog: issue tile t0 into buf 0 (no wait yet)
    if (tfirst < ntile) stage_tile(xb + tfirst * TILE_B, lds, lane);

    int p = 0;
    for (long long t = tfirst; t < ntile; t += GW, p ^= 1) {
        const long long tn = t + GW;
        if (tn < ntile) {
            // issue next tile's 38 loads into the other buffer, then wait for
            // THIS tile only: in-order vmcnt retirement -> vmcnt(38) drains
            // everything older than the just-issued batch (incl. old stores).
            stage_tile(xb + tn * TILE_B, lds + (p ^ 1) * TILE_B, lane);
            asm volatile("s_waitcnt vmcnt(38)" ::: "memory");
        } else {
            asm volatile("s_waitcnt vmcnt(0)" ::: "memory");
        }
        __builtin_amdgcn_sched_barrier(0);   // pin LDS reads after the wait

        const float* row = (const float*)(lds + p * TILE_B) + lane * RL;
        float o[NK];
        compute_row(row, o);
        float* __restrict__ dst = out + (t * RTILE + lane) * NK;
        dst[0] = o[0]; dst[1] = o[1]; dst[2] = o[2];
    }

    // remainder rows (nrows % 64) — generality; zero iterations for N=2e6.
    if (blockIdx.x == 0) {
        for (int r = ntile * RTILE + lane; r < nrows; r += 64) {
            const float* row = x + (long long)r * RL;  // direct global, tiny
            float o[NK];
            compute_row(row, o);
            float* dst = out + (long long)r * NK;
            dst[0] = o[0]; dst[1] = o[1]; dst[2] = o[2];
        }
    }
}

extern "C" void kernel_launch(void* const* d_in, const int* in_sizes, int n_in,
                              void* d_out, int out_size, void* d_ws, size_t ws_size,
                              hipStream_t stream) {
    const float* x = (const float*)d_in[0];
    float* out = (float*)d_out;
    const int nrows = in_sizes[0] / RL;
    ope_kernel<<<GRID, 64, 0, stream>>>(x, out, nrows);
}

// Round 4
// 219.452 us; speedup vs baseline: 1.0182x; 1.0182x over previous
//
#include <hip/hip_runtime.h>
#include <stdint.h>
#include <math.h>

// LC_OPE: per-row Fourier outer-product embedding contraction.
// out[n,k] = (1/100) * sum_{i,j} X[n,i]*Y[n,j]*lat[n,k,i*7+j]
//
// R4: persistent barrier-free pipeline. 1 wave per block, 32-row tile
// (19072 B) double-buffered, 4 blocks/CU exactly resident (grid=1024,
// single residency round, ~61 iterations/block). Counted s_waitcnt
// vmcnt(19) keeps next tile's loads in flight across compute; 4
// independent staggered waves/CU keep HBM saturated.

#define RL      149
#define RTILE   32                      // rows per tile
#define TILE_B  (RTILE * RL * 4)        // 19072 B
#define FULLCH  18                      // 18 x 1024 B = 18432 B
#define OVOFF   (TILE_B - 1024)        // 18048: overlapping tail chunk (640 B new, 384 B L2 re-read)
#define NLOAD   19
#define GRID    1024                    // 4 blocks/CU x 256 CU
#define NK      3

typedef const __attribute__((address_space(1))) unsigned int as1_uint;
typedef __attribute__((address_space(3))) unsigned int as3_uint;

__device__ __forceinline__ void stage_tile(const char* __restrict__ src,
                                           char* dst, int lane) {
    // 19 wave-instructions, each 64 lanes x 16 B = 1024 B, linear LDS dest.
    #pragma unroll
    for (int ci = 0; ci < FULLCH; ++ci)
        __builtin_amdgcn_global_load_lds((as1_uint*)(src + ci * 1024 + lane * 16),
                                         (as3_uint*)(dst + ci * 1024), 16, 0, 0);
    __builtin_amdgcn_global_load_lds((as1_uint*)(src + OVOFF + lane * 16),
                                     (as3_uint*)(dst + OVOFF), 16, 0, 0);
}

__device__ __forceinline__ void compute_row(const float* __restrict__ row,
                                            float* __restrict__ dst) {
    const float OMEGA = 1.5707963267948966f;  // pi/2
    const float S2    = 1.4142135623730951f;  // sqrt(2)
    const float t0 = row[147] * OMEGA;
    const float t1 = row[148] * OMEGA;
    float X[7], Y[7];
    X[0] = 1.f; Y[0] = 1.f;
    #pragma unroll
    for (int f = 1; f <= 3; ++f) {            // fully unrolled -> static X/Y indexing
        float s, c;
        __sincosf(t0 * (float)f, &s, &c);
        X[2*f-1] = S2 * c; X[2*f] = S2 * s;
        __sincosf(t1 * (float)f, &s, &c);
        Y[2*f-1] = S2 * c; Y[2*f] = S2 * s;
    }
    float a0 = 0.f, a1 = 0.f, a2 = 0.f;
    #pragma unroll
    for (int i = 0; i < 7; ++i)
        #pragma unroll
        for (int j = 0; j < 7; ++j) {
            const float p = X[i] * Y[j];
            const int c = i * 7 + j;
            a0 = fmaf(p, row[c],      a0);
            a1 = fmaf(p, row[49 + c], a1);
            a2 = fmaf(p, row[98 + c], a2);
        }
    dst[0] = a0 * 0.01f; dst[1] = a1 * 0.01f; dst[2] = a2 * 0.01f;
}

__global__ __launch_bounds__(64)
void ope_kernel(const float* __restrict__ x, float* __restrict__ out, int nrows) {
    __shared__ __align__(16) char lds[2 * TILE_B];   // 38144 B -> 4 blocks/CU
    const int lane = threadIdx.x;                    // one wave per block
    const char* __restrict__ xb = (const char*)x;
    const int ntile = nrows / RTILE;                 // 62500 for N=2e6 (exact)
    const long long tfirst = blockIdx.x;
    const int GW = gridDim.x;

    // prolog: issue tile t0 into buf 0 (no wait yet)
    if (tfirst < ntile) stage_tile(xb + tfirst * TILE_B, lds, lane);

    int p = 0;
    for (long long t = tfirst; t < ntile; t += GW, p ^= 1) {
        const long long tn = t + GW;
        if (tn < ntile) {
            // Issue next tile's 19 loads into the other buffer, then wait
            // until only those 19 remain: in-order per-wave vmem retirement
            // drains tile t's loads (issued a full iteration ago) and the
            // previous iteration's 3 stores.
            stage_tile(xb + tn * TILE_B, lds + (p ^ 1) * TILE_B, lane);
            asm volatile("s_waitcnt vmcnt(19)" ::: "memory");
        } else {
            asm volatile("s_waitcnt vmcnt(0)" ::: "memory");
        }
        __builtin_amdgcn_sched_barrier(0);   // pin LDS reads after the wait

        if (lane < RTILE) {                  // lanes 0..31 compute, 1 row each
            const float* row = (const float*)(lds + p * TILE_B) + lane * RL;
            float o[NK];
            compute_row(row, o);
            float* __restrict__ dst = out + (t * RTILE + lane) * NK;
            dst[0] = o[0]; dst[1] = o[1]; dst[2] = o[2];   // 384 B contiguous/wave
        }
    }

    // remainder rows (nrows % 32) — generality; zero iterations for N=2e6.
    if (blockIdx.x == 0) {
        for (int r = ntile * RTILE + lane; r < nrows; r += 64) {
            const float* row = x + (long long)r * RL;   // direct global, tiny
            float o[NK];
            compute_row(row, o);
            float* dst = out + (long long)r * NK;
            dst[0] = o[0]; dst[1] = o[1]; dst[2] = o[2];
        }
    }
}

extern "C" void kernel_launch(void* const* d_in, const int* in_sizes, int n_in,
                              void* d_out, int out_size, void* d_ws, size_t ws_size,
                              hipStream_t stream) {
    const float* x = (const float*)d_in[0];
    float* out = (float*)d_out;
    const int nrows = in_sizes[0] / RL;
    ope_kernel<<<GRID, 64, 0, stream>>>(x, out, nrows);
}

// Round 5
// 213.221 us; speedup vs baseline: 1.0479x; 1.0292x over previous
//
#include <hip/hip_runtime.h>
#include <stdint.h>
#include <math.h>

// LC_OPE: per-row Fourier outer-product embedding contraction.
// out[n,k] = (1/100) * sum_{i,j} X[n,i]*Y[n,j]*lat[n,k,i*7+j]
//
// R5: maximize independent memory streams. One wave per block, one-shot
// 32-row tile (19072 B LDS) -> 8 blocks resident per CU, no barriers
// (single-wave block: one explicit s_waitcnt vmcnt(0) orders
// global_load_lds -> ds_read). 8 staggered slots/CU hide each other's
// wait/compute/store dead time.

#define RL      149
#define RTILE   32                      // rows per block
#define TILE_B  (RTILE * RL * 4)        // 19072 B -> 8 blocks/CU (LDS-limited)
#define FULLCH  18                      // 18 x 1024 B = 18432 B
#define OVOFF   (TILE_B - 1024)         // 18048: overlapping tail chunk (L2 re-read, no extra HBM)
#define NK      3

typedef const __attribute__((address_space(1))) unsigned int as1_uint;
typedef __attribute__((address_space(3))) unsigned int as3_uint;

__device__ __forceinline__ void compute_row(const float* __restrict__ row,
                                            float* __restrict__ dst) {
    const float OMEGA = 1.5707963267948966f;  // pi/2
    const float S2    = 1.4142135623730951f;  // sqrt(2)
    const float t0 = row[147] * OMEGA;
    const float t1 = row[148] * OMEGA;
    float X[7], Y[7];
    X[0] = 1.f; Y[0] = 1.f;
    #pragma unroll
    for (int f = 1; f <= 3; ++f) {            // fully unrolled -> static X/Y indexing
        float s, c;
        __sincosf(t0 * (float)f, &s, &c);
        X[2*f-1] = S2 * c; X[2*f] = S2 * s;
        __sincosf(t1 * (float)f, &s, &c);
        Y[2*f-1] = S2 * c; Y[2*f] = S2 * s;
    }
    float a0 = 0.f, a1 = 0.f, a2 = 0.f;
    #pragma unroll
    for (int i = 0; i < 7; ++i)
        #pragma unroll
        for (int j = 0; j < 7; ++j) {
            const float p = X[i] * Y[j];
            const int c = i * 7 + j;
            a0 = fmaf(p, row[c],      a0);
            a1 = fmaf(p, row[49 + c], a1);
            a2 = fmaf(p, row[98 + c], a2);
        }
    dst[0] = a0 * 0.01f; dst[1] = a1 * 0.01f; dst[2] = a2 * 0.01f;
}

__global__ __launch_bounds__(64)
void ope_kernel(const float* __restrict__ x, float* __restrict__ out, int nrows) {
    __shared__ __align__(16) char lds[TILE_B];
    const int lane = threadIdx.x;               // one wave per block
    const long long row0 = (long long)blockIdx.x * RTILE;
    const int vr_full = (row0 + RTILE <= nrows);

    if (vr_full) {
        const char* __restrict__ src = (const char*)x + row0 * RL * 4; // 19072*b: 16B-aligned
        // 19 wave-instructions, each 64 lanes x 16 B = 1024 B, linear LDS dest.
        #pragma unroll
        for (int ci = 0; ci < FULLCH; ++ci)
            __builtin_amdgcn_global_load_lds((as1_uint*)(src + ci * 1024 + lane * 16),
                                             (as3_uint*)(lds + ci * 1024), 16, 0, 0);
        __builtin_amdgcn_global_load_lds((as1_uint*)(src + OVOFF + lane * 16),
                                         (as3_uint*)(lds + OVOFF), 16, 0, 0);
        asm volatile("s_waitcnt vmcnt(0)" ::: "memory");
        __builtin_amdgcn_sched_barrier(0);      // keep ds_reads after the wait

        if (lane < RTILE) {
            const float* row = (const float*)lds + lane * RL; // stride-149: 2-way bank alias, free
            float o[NK];
            compute_row(row, o);
            float* __restrict__ dst = out + (row0 + lane) * NK;
            dst[0] = o[0]; dst[1] = o[1]; dst[2] = o[2];      // 384 B contiguous burst
        }
    } else {
        // partial last tile (nrows % 32 != 0) — defensive; absent for N=2e6
        for (int r = (int)row0 + lane; r < nrows; r += 64) {
            const float* row = x + (long long)r * RL;
            float o[NK];
            compute_row(row, o);
            float* dst = out + (long long)r * NK;
            dst[0] = o[0]; dst[1] = o[1]; dst[2] = o[2];
        }
    }
}

extern "C" void kernel_launch(void* const* d_in, const int* in_sizes, int n_in,
                              void* d_out, int out_size, void* d_ws, size_t ws_size,
                              hipStream_t stream) {
    const float* x = (const float*)d_in[0];
    float* out = (float*)d_out;
    const int nrows = in_sizes[0] / RL;
    const int grid = (nrows + RTILE - 1) / RTILE;
    ope_kernel<<<grid, 64, 0, stream>>>(x, out, nrows);
}